// Round 5
// baseline (205.327 us; speedup 1.0000x reference)
//
#include <hip/hip_runtime.h>
#include <math.h>

// Problem constants (from reference)
#define NN 10000
#define INF 512
#define HF  512
#define OF  64
#define NE  163840

typedef __attribute__((ext_vector_type(8))) short bf16x8_t;   // 8 bf16 = 4 VGPRs
typedef __attribute__((ext_vector_type(4))) float f32x4_t;    // 4 fp32 acc

__device__ inline ushort f2bf(float f) {
    unsigned u = __float_as_uint(f);
    u = (u + 0x7FFF + ((u >> 16) & 1)) >> 16;   // RNE
    return (ushort)u;
}
__device__ inline float bf2f(ushort u) {
    return __uint_as_float(((unsigned)u) << 16);
}

// ---------------- fused preprocessing: zero + count + scan (1 block) ----------------
// NN=10000 int histogram fits in 40 KB LDS. 1024 threads:
// phase 1: zero LDS hist; phase 2: E coalesced dst reads + LDS atomics;
// phase 3: chunked shfl scan -> row_start/cursor/dinv.
__global__ __launch_bounds__(1024) void k_pre(const int* __restrict__ dst, int E,
                                              int* __restrict__ row_start,
                                              int* __restrict__ cursor,
                                              float* __restrict__ dinv) {
    __shared__ int hist[NN];
    __shared__ int wsum[16];
    int t = threadIdx.x;
    for (int i = t; i < NN; i += 1024) hist[i] = 0;
    __syncthreads();
    for (int e = t; e < E; e += 1024) atomicAdd(&hist[dst[e]], 1);
    __syncthreads();
    int lane = t & 63, wv = t >> 6;
    const int CH = (NN + 1023) >> 10;         // 10
    int begin = t * CH; if (begin > NN) begin = NN;
    int end = begin + CH; if (end > NN) end = NN;
    int s = 0;
    for (int i = begin; i < end; i++) s += hist[i];
    int incl = s;
#pragma unroll
    for (int off = 1; off < 64; off <<= 1) {
        int u = __shfl_up(incl, off, 64);
        if (lane >= off) incl += u;
    }
    if (lane == 63) wsum[wv] = incl;
    __syncthreads();
    int woff = 0;
    for (int i = 0; i < wv; i++) woff += wsum[i];
    int excl = woff + incl - s;
    for (int i = begin; i < end; i++) {
        row_start[i] = excl;
        cursor[i] = excl;
        int c = hist[i];
        excl += c;
        dinv[i] = rsqrtf((float)(c + 1));     // +1 self-loop; always > 0
    }
    if (t == 1023) row_start[NN] = woff + incl;
}

// ---------------- fused conversions + CSR fill (grid-partitioned) ----------------
// blocks [0,2500): x fp32->bf16 (8 elems/thread)
// blocks [2500,2756): W1 [512,512] transpose+cvt -> W1T bf16 [n][k]
// blocks [2756,2788): W2 [512,64] transpose+cvt -> W2T bf16 [n][k]
// blocks [2788,3428): CSR fill (640*256 = NE exactly)
#define CVT_XB   2500
#define CVT_W1B  2756
#define CVT_W2B  2788
#define CVT_ALLB 3428
__global__ __launch_bounds__(256) void k_cvt_fill(const float* __restrict__ X,
                                                  ushort* __restrict__ Xb,
                                                  const float* __restrict__ W1,
                                                  ushort* __restrict__ W1T,
                                                  const float* __restrict__ W2,
                                                  ushort* __restrict__ W2T,
                                                  const int* __restrict__ src,
                                                  const int* __restrict__ dst,
                                                  const float* __restrict__ dinv,
                                                  int* __restrict__ cursor,
                                                  int* __restrict__ csr_src,
                                                  float* __restrict__ csr_w) {
    __shared__ float tl[32][33];
    int b = blockIdx.x, t = threadIdx.x;
    if (b < CVT_XB) {
        int i = (b * 256 + t) * 2;
        const float4* Xv = (const float4*)X;
        float4 v0 = Xv[i], v1 = Xv[i + 1];
        ushort4 o0, o1;
        o0.x = f2bf(v0.x); o0.y = f2bf(v0.y); o0.z = f2bf(v0.z); o0.w = f2bf(v0.w);
        o1.x = f2bf(v1.x); o1.y = f2bf(v1.y); o1.z = f2bf(v1.z); o1.w = f2bf(v1.w);
        ((ushort4*)Xb)[i] = o0;
        ((ushort4*)Xb)[i + 1] = o1;
    } else if (b < CVT_W2B) {
        const float* W; ushort* WT; int N, tile;
        if (b < CVT_W1B) { W = W1; WT = W1T; N = 512; tile = b - CVT_XB; }
        else             { W = W2; WT = W2T; N = 64;  tile = b - CVT_W1B; }
        int k0 = (tile & 15) * 32;
        int n0 = (tile >> 4) * 32;
        int tx = t & 31, ty = t >> 5;            // ty 0..7
#pragma unroll
        for (int i = 0; i < 4; i++)
            tl[ty + i * 8][tx] = W[(size_t)(k0 + ty + i * 8) * N + n0 + tx];
        __syncthreads();
#pragma unroll
        for (int i = 0; i < 4; i++)
            WT[(size_t)(n0 + ty + i * 8) * 512 + k0 + tx] = f2bf(tl[tx][ty + i * 8]);
    } else {
        int e = (b - CVT_W2B) * 256 + t;         // < NE by construction
        int s = src[e], d = dst[e];
        int p = atomicAdd(&cursor[d], 1);
        csr_src[p] = s;
        csr_w[p] = dinv[s] * dinv[d];
    }
}

// ---------------- MFMA GEMM1: Xb[NN,512] @ W1T[512,512](T) -> h1b[NN,512] bf16 ----------
#define LDA 72
__global__ __launch_bounds__(256) void k_gemm_mfma(const ushort* __restrict__ Xb,
                                                   const ushort* __restrict__ WT,
                                                   ushort* __restrict__ Y) {
    __shared__ ushort As[64 * LDA];
    __shared__ ushort Bs[128 * LDA];
    int tid = threadIdx.x;
    int lane = tid & 63;
    int wave = tid >> 6;
    int m = lane & 15;
    int q = lane >> 4;
    int wr = wave >> 1;
    int wc = wave & 1;
    int row0 = blockIdx.x * 64;
    int col0 = blockIdx.y * 128;

    f32x4_t acc[2][4];
#pragma unroll
    for (int r = 0; r < 2; r++)
#pragma unroll
        for (int c = 0; c < 4; c++) acc[r][c] = (f32x4_t){0.f, 0.f, 0.f, 0.f};

    int srow = tid >> 3;
    int skk = (tid & 7) * 8;

    for (int kb = 0; kb < 512; kb += 64) {
#pragma unroll
        for (int c_ = 0; c_ < 2; c_++) {
            int row = srow + c_ * 32;
            int grow = row0 + row;
            bf16x8_t v = {0, 0, 0, 0, 0, 0, 0, 0};
            if (grow < NN)
                v = *(const bf16x8_t*)(Xb + (size_t)grow * 512 + kb + skk);
            *(bf16x8_t*)(As + row * LDA + skk) = v;
        }
#pragma unroll
        for (int c_ = 0; c_ < 4; c_++) {
            int n = srow + c_ * 32;
            bf16x8_t v = *(const bf16x8_t*)(WT + (size_t)(col0 + n) * 512 + kb + skk);
            *(bf16x8_t*)(Bs + n * LDA + skk) = v;
        }
        __syncthreads();
#pragma unroll
        for (int kc = 0; kc < 2; kc++) {
            bf16x8_t a[2], b[4];
#pragma unroll
            for (int r = 0; r < 2; r++)
                a[r] = *(const bf16x8_t*)(As + (wr * 32 + r * 16 + m) * LDA + kc * 32 + q * 8);
#pragma unroll
            for (int c = 0; c < 4; c++)
                b[c] = *(const bf16x8_t*)(Bs + (wc * 64 + c * 16 + m) * LDA + kc * 32 + q * 8);
#pragma unroll
            for (int r = 0; r < 2; r++)
#pragma unroll
                for (int c = 0; c < 4; c++)
                    acc[r][c] = __builtin_amdgcn_mfma_f32_16x16x32_bf16(a[r], b[c], acc[r][c], 0, 0, 0);
        }
        __syncthreads();
    }
#pragma unroll
    for (int r = 0; r < 2; r++) {
#pragma unroll
        for (int c = 0; c < 4; c++) {
#pragma unroll
            for (int reg = 0; reg < 4; reg++) {
                int row = row0 + wr * 32 + r * 16 + q * 4 + reg;
                int col = col0 + wc * 64 + c * 16 + m;
                if (row < NN) Y[(size_t)row * 512 + col] = f2bf(acc[r][c][reg]);
            }
        }
    }
}

// ---------------- MFMA GEMM2: a1b[NN,512] @ W2T[64,512](T) -> h2b[NN,64] bf16 ----------
__global__ __launch_bounds__(256) void k_gemm64_mfma(const ushort* __restrict__ Ab,
                                                     const ushort* __restrict__ W2T,
                                                     ushort* __restrict__ Y) {
    __shared__ ushort As[64 * LDA];
    __shared__ ushort Bs[64 * LDA];
    int tid = threadIdx.x;
    int lane = tid & 63;
    int wave = tid >> 6;
    int m = lane & 15;
    int q = lane >> 4;
    int row0 = blockIdx.x * 64;

    f32x4_t acc[4];
#pragma unroll
    for (int c = 0; c < 4; c++) acc[c] = (f32x4_t){0.f, 0.f, 0.f, 0.f};

    int srow = tid >> 3;
    int skk = (tid & 7) * 8;

    for (int kb = 0; kb < 512; kb += 64) {
#pragma unroll
        for (int c_ = 0; c_ < 2; c_++) {
            int row = srow + c_ * 32;
            int grow = row0 + row;
            bf16x8_t v = {0, 0, 0, 0, 0, 0, 0, 0};
            if (grow < NN)
                v = *(const bf16x8_t*)(Ab + (size_t)grow * 512 + kb + skk);
            *(bf16x8_t*)(As + row * LDA + skk) = v;
            bf16x8_t wv = *(const bf16x8_t*)(W2T + (size_t)row * 512 + kb + skk);
            *(bf16x8_t*)(Bs + row * LDA + skk) = wv;
        }
        __syncthreads();
#pragma unroll
        for (int kc = 0; kc < 2; kc++) {
            bf16x8_t a = *(const bf16x8_t*)(As + (wave * 16 + m) * LDA + kc * 32 + q * 8);
#pragma unroll
            for (int c = 0; c < 4; c++) {
                bf16x8_t b = *(const bf16x8_t*)(Bs + (c * 16 + m) * LDA + kc * 32 + q * 8);
                acc[c] = __builtin_amdgcn_mfma_f32_16x16x32_bf16(a, b, acc[c], 0, 0, 0);
            }
        }
        __syncthreads();
    }
#pragma unroll
    for (int c = 0; c < 4; c++) {
#pragma unroll
        for (int reg = 0; reg < 4; reg++) {
            int row = row0 + wave * 16 + q * 4 + reg;
            int col = c * 16 + m;
            if (row < NN) Y[(size_t)row * 64 + col] = f2bf(acc[c][reg]);
        }
    }
}

// ---------------- aggregate layer 1: XCD-affine slices + 8-deep MLP ----------------
__global__ __launch_bounds__(64) void k_agg1(const ushort* __restrict__ h1b,
                                             const int* __restrict__ row_start,
                                             const int* __restrict__ csr_src,
                                             const float* __restrict__ csr_w,
                                             const float* __restrict__ dinv,
                                             const float* __restrict__ b,
                                             ushort* __restrict__ a1b) {
    __shared__ int   sidx[64];
    __shared__ float swt[64];
    int bid = blockIdx.x;
    int slice = bid & 7;
    int v = bid >> 3;
    int t = threadIdx.x;
    int f = slice * 64 + t;
    float dv = dinv[v];
    int beg = row_start[v], end = row_start[v + 1];
    float acc[8];
#pragma unroll
    for (int k = 0; k < 8; k++) acc[k] = 0.f;
    acc[0] = bf2f(h1b[(size_t)v * 512 + f]) * (dv * dv);   // self-loop

    for (int chunk = beg; chunk < end; chunk += 64) {
        int j = chunk + t;
        if (j < end) { sidx[t] = csr_src[j]; swt[t] = csr_w[j]; }
        else         { sidx[t] = 0;          swt[t] = 0.f; }
        __syncthreads();
        int n = end - chunk; if (n > 64) n = 64;
        int nr = (n + 7) & ~7;                 // round to 8; extras have w=0
        for (int i = 0; i < nr; i += 8) {
            int   sK[8]; float wK[8];
#pragma unroll
            for (int k = 0; k < 8; k++) { sK[k] = sidx[i + k]; wK[k] = swt[i + k]; }
#pragma unroll
            for (int k = 0; k < 8; k++)
                acc[k] += bf2f(h1b[(size_t)sK[k] * 512 + f]) * wK[k];
        }
        __syncthreads();
    }
    float total = ((acc[0] + acc[1]) + (acc[2] + acc[3])) +
                  ((acc[4] + acc[5]) + (acc[6] + acc[7]));
    total += b[f];
    a1b[(size_t)v * 512 + f] = f2bf(total > 0.f ? total : 0.f);
}

// ---------------- aggregate layer 2 + bias + log_softmax ----------------
__global__ __launch_bounds__(64) void k_agg2_lsm(const ushort* __restrict__ h2b,
                                                 const int* __restrict__ row_start,
                                                 const int* __restrict__ csr_src,
                                                 const float* __restrict__ csr_w,
                                                 const float* __restrict__ dinv,
                                                 const float* __restrict__ b,
                                                 float* __restrict__ out) {
    __shared__ int   sidx[64];
    __shared__ float swt[64];
    int v = blockIdx.x;
    int t = threadIdx.x;
    float dv = dinv[v];
    int beg = row_start[v], end = row_start[v + 1];
    float acc[8];
#pragma unroll
    for (int k = 0; k < 8; k++) acc[k] = 0.f;
    acc[0] = bf2f(h2b[(size_t)v * 64 + t]) * (dv * dv);

    for (int chunk = beg; chunk < end; chunk += 64) {
        int j = chunk + t;
        if (j < end) { sidx[t] = csr_src[j]; swt[t] = csr_w[j]; }
        else         { sidx[t] = 0;          swt[t] = 0.f; }
        __syncthreads();
        int n = end - chunk; if (n > 64) n = 64;
        int nr = (n + 7) & ~7;
        for (int i = 0; i < nr; i += 8) {
            int   sK[8]; float wK[8];
#pragma unroll
            for (int k = 0; k < 8; k++) { sK[k] = sidx[i + k]; wK[k] = swt[i + k]; }
#pragma unroll
            for (int k = 0; k < 8; k++)
                acc[k] += bf2f(h2b[(size_t)sK[k] * 64 + t]) * wK[k];
        }
        __syncthreads();
    }
    float h = ((acc[0] + acc[1]) + (acc[2] + acc[3])) +
              ((acc[4] + acc[5]) + (acc[6] + acc[7]));
    h += b[t];
    out[(size_t)v * 64 + t] = h;           // output 0: h
    float m = h;
#pragma unroll
    for (int off = 32; off >= 1; off >>= 1) m = fmaxf(m, __shfl_xor(m, off, 64));
    float e = expf(h - m);
    float ssum = e;
#pragma unroll
    for (int off = 32; off >= 1; off >>= 1) ssum += __shfl_xor(ssum, off, 64);
    out[(size_t)NN * OF + (size_t)v * 64 + t] = h - m - logf(ssum);  // output 1
}

// ---------------- launch ----------------

extern "C" void kernel_launch(void* const* d_in, const int* in_sizes, int n_in,
                              void* d_out, int out_size, void* d_ws, size_t ws_size,
                              hipStream_t stream) {
    const float* x  = (const float*)d_in[0];
    const int*   ei = (const int*)d_in[1];
    const float* W1 = (const float*)d_in[2];
    const float* b1 = (const float*)d_in[3];
    const float* W2 = (const float*)d_in[4];
    const float* b2 = (const float*)d_in[5];
    float* out = (float*)d_out;

    const int E = in_sizes[1] / 2;       // 163840
    const int* src = ei;
    const int* dst = ei + E;

    char* w = (char*)d_ws;
    auto carve = [&](size_t bytes) {
        char* p = w;
        w += (bytes + 255) & ~size_t(255);
        return p;
    };
    ushort* Xb     = (ushort*)carve((size_t)NN * 512 * 2);
    ushort* h1b    = (ushort*)carve((size_t)NN * 512 * 2);
    ushort* a1b    = (ushort*)carve((size_t)NN * 512 * 2);
    ushort* h2b    = (ushort*)carve((size_t)NN * 64 * 2);
    ushort* W1Tb   = (ushort*)carve((size_t)512 * 512 * 2);
    ushort* W2Tb   = (ushort*)carve((size_t)64 * 512 * 2);
    int*   rstart  = (int*)carve((size_t)(NN + 1) * 4);
    int*   cursor  = (int*)carve((size_t)NN * 4);
    int*   csr_src = (int*)carve((size_t)NE * 4);
    float* csr_w   = (float*)carve((size_t)NE * 4);
    float* dinv    = (float*)carve((size_t)NN * 4);
    (void)ws_size;

    // 6 dispatches total (was 11): launch overhead was the hidden whale.
    k_pre<<<1, 1024, 0, stream>>>(dst, E, rstart, cursor, dinv);
    k_cvt_fill<<<CVT_ALLB, 256, 0, stream>>>(x, Xb, W1, W1Tb, W2, W2Tb,
                                             src, dst, dinv, cursor, csr_src, csr_w);
    k_gemm_mfma<<<dim3((NN + 63) / 64, 4), 256, 0, stream>>>(Xb, W1Tb, h1b);
    k_agg1<<<NN * 8, 64, 0, stream>>>(h1b, rstart, csr_src, csr_w, dinv, b1, a1b);
    k_gemm64_mfma<<<(NN + 63) / 64, 256, 0, stream>>>(a1b, W2Tb, h2b);
    k_agg2_lsm<<<NN, 64, 0, stream>>>(h2b, rstart, csr_src, csr_w, dinv, b2, out);
}

// Round 6
// 172.800 us; speedup vs baseline: 1.1882x; 1.1882x over previous
//
#include <hip/hip_runtime.h>
#include <math.h>

// Problem constants (from reference)
#define NN 10000
#define INF 512
#define HF  512
#define OF  64
#define NE  163840

typedef __attribute__((ext_vector_type(8))) short bf16x8_t;   // 8 bf16 = 4 VGPRs
typedef __attribute__((ext_vector_type(4))) float f32x4_t;    // 4 fp32 acc

__device__ inline ushort f2bf(float f) {
    unsigned u = __float_as_uint(f);
    u = (u + 0x7FFF + ((u >> 16) & 1)) >> 16;   // RNE
    return (ushort)u;
}
__device__ inline float bf2f(ushort u) {
    return __uint_as_float(((unsigned)u) << 16);
}

// ---------------- fused preprocessing: zero + count + scan (1 block) ----------------
// Histogram phase is latency-bound on 1 CU -> int4 loads + 8-deep unroll keeps
// 32 edges in flight per thread (R4: serial load->atomic chain cost 70 us).
__global__ __launch_bounds__(1024) void k_pre(const int* __restrict__ dst, int E,
                                              int* __restrict__ row_start,
                                              int* __restrict__ cursor,
                                              float* __restrict__ dinv) {
    __shared__ int hist[NN];
    __shared__ int wsum[16];
    int t = threadIdx.x;
    for (int i = t; i < NN; i += 1024) hist[i] = 0;
    __syncthreads();

    // --- histogram: vectorized + MLP-unrolled ---
    const int M = E >> 2;                      // int4 count (40960 for NE)
    const int4* d4 = (const int4*)dst;
    int base = t;
    for (; base + 7 * 1024 < M; base += 8 * 1024) {
        int4 v[8];
#pragma unroll
        for (int k = 0; k < 8; k++) v[k] = d4[base + k * 1024];
#pragma unroll
        for (int k = 0; k < 8; k++) {
            atomicAdd(&hist[v[k].x], 1);
            atomicAdd(&hist[v[k].y], 1);
            atomicAdd(&hist[v[k].z], 1);
            atomicAdd(&hist[v[k].w], 1);
        }
    }
    for (; base < M; base += 1024) {
        int4 v = d4[base];
        atomicAdd(&hist[v.x], 1);
        atomicAdd(&hist[v.y], 1);
        atomicAdd(&hist[v.z], 1);
        atomicAdd(&hist[v.w], 1);
    }
    for (int e = (M << 2) + t; e < E; e += 1024) atomicAdd(&hist[dst[e]], 1);
    __syncthreads();

    // --- scan ---
    int lane = t & 63, wv = t >> 6;
    const int CH = (NN + 1023) >> 10;         // 10
    int begin = t * CH; if (begin > NN) begin = NN;
    int end = begin + CH; if (end > NN) end = NN;
    int s = 0;
    for (int i = begin; i < end; i++) s += hist[i];
    int incl = s;
#pragma unroll
    for (int off = 1; off < 64; off <<= 1) {
        int u = __shfl_up(incl, off, 64);
        if (lane >= off) incl += u;
    }
    if (lane == 63) wsum[wv] = incl;
    __syncthreads();
    int woff = 0;
    for (int i = 0; i < wv; i++) woff += wsum[i];
    int excl = woff + incl - s;
    for (int i = begin; i < end; i++) {
        row_start[i] = excl;
        cursor[i] = excl;
        int c = hist[i];
        excl += c;
        dinv[i] = rsqrtf((float)(c + 1));     // +1 self-loop; always > 0
    }
    if (t == 1023) row_start[NN] = woff + incl;
}

// ---------------- fused conversions + CSR fill (grid-partitioned) ----------------
// blocks [0,2500): x fp32->bf16 (8 elems/thread)
// blocks [2500,2756): W1 [512,512] transpose+cvt -> W1T bf16 [n][k]
// blocks [2756,2788): W2 [512,64] transpose+cvt -> W2T bf16 [n][k]
// blocks [2788,3428): CSR fill (640*256 = NE exactly)
#define CVT_XB   2500
#define CVT_W1B  2756
#define CVT_W2B  2788
#define CVT_ALLB 3428
__global__ __launch_bounds__(256) void k_cvt_fill(const float* __restrict__ X,
                                                  ushort* __restrict__ Xb,
                                                  const float* __restrict__ W1,
                                                  ushort* __restrict__ W1T,
                                                  const float* __restrict__ W2,
                                                  ushort* __restrict__ W2T,
                                                  const int* __restrict__ src,
                                                  const int* __restrict__ dst,
                                                  const float* __restrict__ dinv,
                                                  int* __restrict__ cursor,
                                                  int* __restrict__ csr_src,
                                                  float* __restrict__ csr_w) {
    __shared__ float tl[32][33];
    int b = blockIdx.x, t = threadIdx.x;
    if (b < CVT_XB) {
        int i = (b * 256 + t) * 2;
        const float4* Xv = (const float4*)X;
        float4 v0 = Xv[i], v1 = Xv[i + 1];
        ushort4 o0, o1;
        o0.x = f2bf(v0.x); o0.y = f2bf(v0.y); o0.z = f2bf(v0.z); o0.w = f2bf(v0.w);
        o1.x = f2bf(v1.x); o1.y = f2bf(v1.y); o1.z = f2bf(v1.z); o1.w = f2bf(v1.w);
        ((ushort4*)Xb)[i] = o0;
        ((ushort4*)Xb)[i + 1] = o1;
    } else if (b < CVT_W2B) {
        const float* W; ushort* WT; int N, tile;
        if (b < CVT_W1B) { W = W1; WT = W1T; N = 512; tile = b - CVT_XB; }
        else             { W = W2; WT = W2T; N = 64;  tile = b - CVT_W1B; }
        int k0 = (tile & 15) * 32;
        int n0 = (tile >> 4) * 32;
        int tx = t & 31, ty = t >> 5;            // ty 0..7
#pragma unroll
        for (int i = 0; i < 4; i++)
            tl[ty + i * 8][tx] = W[(size_t)(k0 + ty + i * 8) * N + n0 + tx];
        __syncthreads();
#pragma unroll
        for (int i = 0; i < 4; i++)
            WT[(size_t)(n0 + ty + i * 8) * 512 + k0 + tx] = f2bf(tl[tx][ty + i * 8]);
    } else {
        int e = (b - CVT_W2B) * 256 + t;         // < NE by construction
        int s = src[e], d = dst[e];
        int p = atomicAdd(&cursor[d], 1);
        csr_src[p] = s;
        csr_w[p] = dinv[s] * dinv[d];
    }
}

// ---------------- MFMA GEMM1: Xb[NN,512] @ W1T[512,512](T) -> h1b[NN,512] bf16 ----------
#define LDA 72
__global__ __launch_bounds__(256) void k_gemm_mfma(const ushort* __restrict__ Xb,
                                                   const ushort* __restrict__ WT,
                                                   ushort* __restrict__ Y) {
    __shared__ ushort As[64 * LDA];
    __shared__ ushort Bs[128 * LDA];
    int tid = threadIdx.x;
    int lane = tid & 63;
    int wave = tid >> 6;
    int m = lane & 15;
    int q = lane >> 4;
    int wr = wave >> 1;
    int wc = wave & 1;
    int row0 = blockIdx.x * 64;
    int col0 = blockIdx.y * 128;

    f32x4_t acc[2][4];
#pragma unroll
    for (int r = 0; r < 2; r++)
#pragma unroll
        for (int c = 0; c < 4; c++) acc[r][c] = (f32x4_t){0.f, 0.f, 0.f, 0.f};

    int srow = tid >> 3;
    int skk = (tid & 7) * 8;

    for (int kb = 0; kb < 512; kb += 64) {
#pragma unroll
        for (int c_ = 0; c_ < 2; c_++) {
            int row = srow + c_ * 32;
            int grow = row0 + row;
            bf16x8_t v = {0, 0, 0, 0, 0, 0, 0, 0};
            if (grow < NN)
                v = *(const bf16x8_t*)(Xb + (size_t)grow * 512 + kb + skk);
            *(bf16x8_t*)(As + row * LDA + skk) = v;
        }
#pragma unroll
        for (int c_ = 0; c_ < 4; c_++) {
            int n = srow + c_ * 32;
            bf16x8_t v = *(const bf16x8_t*)(WT + (size_t)(col0 + n) * 512 + kb + skk);
            *(bf16x8_t*)(Bs + n * LDA + skk) = v;
        }
        __syncthreads();
#pragma unroll
        for (int kc = 0; kc < 2; kc++) {
            bf16x8_t a[2], b[4];
#pragma unroll
            for (int r = 0; r < 2; r++)
                a[r] = *(const bf16x8_t*)(As + (wr * 32 + r * 16 + m) * LDA + kc * 32 + q * 8);
#pragma unroll
            for (int c = 0; c < 4; c++)
                b[c] = *(const bf16x8_t*)(Bs + (wc * 64 + c * 16 + m) * LDA + kc * 32 + q * 8);
#pragma unroll
            for (int r = 0; r < 2; r++)
#pragma unroll
                for (int c = 0; c < 4; c++)
                    acc[r][c] = __builtin_amdgcn_mfma_f32_16x16x32_bf16(a[r], b[c], acc[r][c], 0, 0, 0);
        }
        __syncthreads();
    }
#pragma unroll
    for (int r = 0; r < 2; r++) {
#pragma unroll
        for (int c = 0; c < 4; c++) {
#pragma unroll
            for (int reg = 0; reg < 4; reg++) {
                int row = row0 + wr * 32 + r * 16 + q * 4 + reg;
                int col = col0 + wc * 64 + c * 16 + m;
                if (row < NN) Y[(size_t)row * 512 + col] = f2bf(acc[r][c][reg]);
            }
        }
    }
}

// ---------------- MFMA GEMM2: a1b[NN,512] @ W2T[64,512](T) -> h2b[NN,64] bf16 ----------
__global__ __launch_bounds__(256) void k_gemm64_mfma(const ushort* __restrict__ Ab,
                                                     const ushort* __restrict__ W2T,
                                                     ushort* __restrict__ Y) {
    __shared__ ushort As[64 * LDA];
    __shared__ ushort Bs[64 * LDA];
    int tid = threadIdx.x;
    int lane = tid & 63;
    int wave = tid >> 6;
    int m = lane & 15;
    int q = lane >> 4;
    int row0 = blockIdx.x * 64;

    f32x4_t acc[4];
#pragma unroll
    for (int c = 0; c < 4; c++) acc[c] = (f32x4_t){0.f, 0.f, 0.f, 0.f};

    int srow = tid >> 3;
    int skk = (tid & 7) * 8;

    for (int kb = 0; kb < 512; kb += 64) {
#pragma unroll
        for (int c_ = 0; c_ < 2; c_++) {
            int row = srow + c_ * 32;
            int grow = row0 + row;
            bf16x8_t v = {0, 0, 0, 0, 0, 0, 0, 0};
            if (grow < NN)
                v = *(const bf16x8_t*)(Ab + (size_t)grow * 512 + kb + skk);
            *(bf16x8_t*)(As + row * LDA + skk) = v;
            bf16x8_t wv = *(const bf16x8_t*)(W2T + (size_t)row * 512 + kb + skk);
            *(bf16x8_t*)(Bs + row * LDA + skk) = wv;
        }
        __syncthreads();
#pragma unroll
        for (int kc = 0; kc < 2; kc++) {
            bf16x8_t a = *(const bf16x8_t*)(As + (wave * 16 + m) * LDA + kc * 32 + q * 8);
#pragma unroll
            for (int c = 0; c < 4; c++) {
                bf16x8_t b = *(const bf16x8_t*)(Bs + (c * 16 + m) * LDA + kc * 32 + q * 8);
                acc[c] = __builtin_amdgcn_mfma_f32_16x16x32_bf16(a, b, acc[c], 0, 0, 0);
            }
        }
        __syncthreads();
    }
#pragma unroll
    for (int c = 0; c < 4; c++) {
#pragma unroll
        for (int reg = 0; reg < 4; reg++) {
            int row = row0 + wave * 16 + q * 4 + reg;
            int col = c * 16 + m;
            if (row < NN) Y[(size_t)row * 64 + col] = f2bf(acc[c][reg]);
        }
    }
}

// ---------------- aggregate layer 1: XCD-affine slices + 8-deep MLP ----------------
__global__ __launch_bounds__(64) void k_agg1(const ushort* __restrict__ h1b,
                                             const int* __restrict__ row_start,
                                             const int* __restrict__ csr_src,
                                             const float* __restrict__ csr_w,
                                             const float* __restrict__ dinv,
                                             const float* __restrict__ b,
                                             ushort* __restrict__ a1b) {
    __shared__ int   sidx[64];
    __shared__ float swt[64];
    int bid = blockIdx.x;
    int slice = bid & 7;
    int v = bid >> 3;
    int t = threadIdx.x;
    int f = slice * 64 + t;
    float dv = dinv[v];
    int beg = row_start[v], end = row_start[v + 1];
    float acc[8];
#pragma unroll
    for (int k = 0; k < 8; k++) acc[k] = 0.f;
    acc[0] = bf2f(h1b[(size_t)v * 512 + f]) * (dv * dv);   // self-loop

    for (int chunk = beg; chunk < end; chunk += 64) {
        int j = chunk + t;
        if (j < end) { sidx[t] = csr_src[j]; swt[t] = csr_w[j]; }
        else         { sidx[t] = 0;          swt[t] = 0.f; }
        __syncthreads();
        int n = end - chunk; if (n > 64) n = 64;
        int nr = (n + 7) & ~7;                 // round to 8; extras have w=0
        for (int i = 0; i < nr; i += 8) {
            int   sK[8]; float wK[8];
#pragma unroll
            for (int k = 0; k < 8; k++) { sK[k] = sidx[i + k]; wK[k] = swt[i + k]; }
#pragma unroll
            for (int k = 0; k < 8; k++)
                acc[k] += bf2f(h1b[(size_t)sK[k] * 512 + f]) * wK[k];
        }
        __syncthreads();
    }
    float total = ((acc[0] + acc[1]) + (acc[2] + acc[3])) +
                  ((acc[4] + acc[5]) + (acc[6] + acc[7]));
    total += b[f];
    a1b[(size_t)v * 512 + f] = f2bf(total > 0.f ? total : 0.f);
}

// ---------------- aggregate layer 2 + bias + log_softmax ----------------
__global__ __launch_bounds__(64) void k_agg2_lsm(const ushort* __restrict__ h2b,
                                                 const int* __restrict__ row_start,
                                                 const int* __restrict__ csr_src,
                                                 const float* __restrict__ csr_w,
                                                 const float* __restrict__ dinv,
                                                 const float* __restrict__ b,
                                                 float* __restrict__ out) {
    __shared__ int   sidx[64];
    __shared__ float swt[64];
    int v = blockIdx.x;
    int t = threadIdx.x;
    float dv = dinv[v];
    int beg = row_start[v], end = row_start[v + 1];
    float acc[8];
#pragma unroll
    for (int k = 0; k < 8; k++) acc[k] = 0.f;
    acc[0] = bf2f(h2b[(size_t)v * 64 + t]) * (dv * dv);

    for (int chunk = beg; chunk < end; chunk += 64) {
        int j = chunk + t;
        if (j < end) { sidx[t] = csr_src[j]; swt[t] = csr_w[j]; }
        else         { sidx[t] = 0;          swt[t] = 0.f; }
        __syncthreads();
        int n = end - chunk; if (n > 64) n = 64;
        int nr = (n + 7) & ~7;
        for (int i = 0; i < nr; i += 8) {
            int   sK[8]; float wK[8];
#pragma unroll
            for (int k = 0; k < 8; k++) { sK[k] = sidx[i + k]; wK[k] = swt[i + k]; }
#pragma unroll
            for (int k = 0; k < 8; k++)
                acc[k] += bf2f(h2b[(size_t)sK[k] * 64 + t]) * wK[k];
        }
        __syncthreads();
    }
    float h = ((acc[0] + acc[1]) + (acc[2] + acc[3])) +
              ((acc[4] + acc[5]) + (acc[6] + acc[7]));
    h += b[t];
    out[(size_t)v * 64 + t] = h;           // output 0: h
    float m = h;
#pragma unroll
    for (int off = 32; off >= 1; off >>= 1) m = fmaxf(m, __shfl_xor(m, off, 64));
    float e = expf(h - m);
    float ssum = e;
#pragma unroll
    for (int off = 32; off >= 1; off >>= 1) ssum += __shfl_xor(ssum, off, 64);
    out[(size_t)NN * OF + (size_t)v * 64 + t] = h - m - logf(ssum);  // output 1
}

// ---------------- launch ----------------

extern "C" void kernel_launch(void* const* d_in, const int* in_sizes, int n_in,
                              void* d_out, int out_size, void* d_ws, size_t ws_size,
                              hipStream_t stream) {
    const float* x  = (const float*)d_in[0];
    const int*   ei = (const int*)d_in[1];
    const float* W1 = (const float*)d_in[2];
    const float* b1 = (const float*)d_in[3];
    const float* W2 = (const float*)d_in[4];
    const float* b2 = (const float*)d_in[5];
    float* out = (float*)d_out;

    const int E = in_sizes[1] / 2;       // 163840
    const int* src = ei;
    const int* dst = ei + E;

    char* w = (char*)d_ws;
    auto carve = [&](size_t bytes) {
        char* p = w;
        w += (bytes + 255) & ~size_t(255);
        return p;
    };
    ushort* Xb     = (ushort*)carve((size_t)NN * 512 * 2);
    ushort* h1b    = (ushort*)carve((size_t)NN * 512 * 2);
    ushort* a1b    = (ushort*)carve((size_t)NN * 512 * 2);
    ushort* h2b    = (ushort*)carve((size_t)NN * 64 * 2);
    ushort* W1Tb   = (ushort*)carve((size_t)512 * 512 * 2);
    ushort* W2Tb   = (ushort*)carve((size_t)64 * 512 * 2);
    int*   rstart  = (int*)carve((size_t)(NN + 1) * 4);
    int*   cursor  = (int*)carve((size_t)NN * 4);
    int*   csr_src = (int*)carve((size_t)NE * 4);
    float* csr_w   = (float*)carve((size_t)NE * 4);
    float* dinv    = (float*)carve((size_t)NN * 4);
    (void)ws_size;

    // 6 dispatches (measured: ~8.6 us/dispatch replay overhead, so stay fused).
    k_pre<<<1, 1024, 0, stream>>>(dst, E, rstart, cursor, dinv);
    k_cvt_fill<<<CVT_ALLB, 256, 0, stream>>>(x, Xb, W1, W1Tb, W2, W2Tb,
                                             src, dst, dinv, cursor, csr_src, csr_w);
    k_gemm_mfma<<<dim3((NN + 63) / 64, 4), 256, 0, stream>>>(Xb, W1Tb, h1b);
    k_agg1<<<NN * 8, 64, 0, stream>>>(h1b, rstart, csr_src, csr_w, dinv, b1, a1b);
    k_gemm64_mfma<<<(NN + 63) / 64, 256, 0, stream>>>(a1b, W2Tb, h2b);
    k_agg2_lsm<<<NN, 64, 0, stream>>>(h2b, rstart, csr_src, csr_w, dinv, b2, out);
}